// Round 11
// baseline (65.264 us; speedup 1.0000x reference)
//
#include <hip/hip_runtime.h>
#include <hip/hip_fp16.h>

#define W 512
#define H 512
#define NSTEPS 256
#define D 256
#define DM1 255.0f
#define QUAD_WS_BYTES (256ull*256ull*256ull*8ull)   // 128 MB fp16-quad volume

struct SetupOut {
    float Rw[9];
    float src[3];
    float kinv[9];
    float sdd;
    float org[3];
    float invsp[3];
};

__device__ __forceinline__ void mat4mul(const float* A, const float* B, float* C) {
    #pragma unroll
    for (int i = 0; i < 4; ++i)
        #pragma unroll
        for (int j = 0; j < 4; ++j) {
            float s = 0.f;
            #pragma unroll
            for (int k = 0; k < 4; ++k) s += A[i*4+k] * B[k*4+j];
            C[i*4+j] = s;
        }
}

__device__ void compute_setup(const float* rt_inv, const float* k_inv, const float* sdd,
                              const float* isocenter, const float* origin, const float* spacing,
                              const float* rot, const float* xyz, SetupOut* o) {
    // --- so3_exp_map ---
    float wx = rot[0], wy = rot[1], wz = rot[2];
    float th2 = wx*wx + wy*wy + wz*wz;
    float th = sqrtf(th2 + 1e-30f);
    float a, b;
    if (th2 > 1e-8f) { a = sinf(th) / th; b = (1.f - cosf(th)) / th2; }
    else             { a = 1.f - th2 / 6.f; b = 0.5f - th2 / 24.f; }
    float K[9]  = {0.f,-wz,wy,  wz,0.f,-wx,  -wy,wx,0.f};
    float K2[9];
    #pragma unroll
    for (int i = 0; i < 3; ++i)
        #pragma unroll
        for (int j = 0; j < 3; ++j) {
            float s = 0.f;
            #pragma unroll
            for (int k = 0; k < 3; ++k) s += K[i*3+k] * K[k*3+j];
            K2[i*3+j] = s;
        }
    float R[9];
    #pragma unroll
    for (int i = 0; i < 9; ++i) R[i] = ((i % 4 == 0) ? 1.f : 0.f) + a*K[i] + b*K2[i];
    float t[3];
    #pragma unroll
    for (int i = 0; i < 3; ++i)
        t[i] = R[i*3+0]*xyz[0] + R[i*3+1]*xyz[1] + R[i*3+2]*xyz[2];

    // --- inv(rtm) via Gauss-Jordan with partial pivoting ---
    float A[16], Ainv[16];
    #pragma unroll
    for (int i = 0; i < 16; ++i) { A[i] = rt_inv[i]; Ainv[i] = 0.f; }
    Ainv[0] = Ainv[5] = Ainv[10] = Ainv[15] = 1.f;
    for (int c = 0; c < 4; ++c) {
        int p = c; float mx = fabsf(A[c*4+c]);
        for (int r = c+1; r < 4; ++r) { float v = fabsf(A[r*4+c]); if (v > mx) { mx = v; p = r; } }
        if (p != c) {
            for (int j = 0; j < 4; ++j) {
                float tmp = A[c*4+j];   A[c*4+j]   = A[p*4+j];   A[p*4+j]   = tmp;
                tmp = Ainv[c*4+j];      Ainv[c*4+j] = Ainv[p*4+j]; Ainv[p*4+j] = tmp;
            }
        }
        float inv = 1.f / A[c*4+c];
        for (int j = 0; j < 4; ++j) { A[c*4+j] *= inv; Ainv[c*4+j] *= inv; }
        for (int r = 0; r < 4; ++r) if (r != c) {
            float f = A[r*4+c];
            for (int j = 0; j < 4; ++j) { A[r*4+j] -= f*A[c*4+j]; Ainv[r*4+j] -= f*Ainv[c*4+j]; }
        }
    }
    float cv[3];
    #pragma unroll
    for (int i = 0; i < 3; ++i)
        cv[i] = Ainv[i*4+0]*isocenter[0] + Ainv[i*4+1]*isocenter[1]
              + Ainv[i*4+2]*isocenter[2] + Ainv[i*4+3];

    // --- pose = rtm @ (piv @ (T @ piv_inv)) ---
    float T[16]    = {R[0],R[1],R[2],t[0],  R[3],R[4],R[5],t[1],  R[6],R[7],R[8],t[2],  0,0,0,1};
    float piv[16]  = {1,0,0, cv[0],  0,1,0, cv[1],  0,0,1, cv[2],  0,0,0,1};
    float pivi[16] = {1,0,0,-cv[0],  0,1,0,-cv[1],  0,0,1,-cv[2],  0,0,0,1};
    float M1[16], M2[16], pose[16];
    mat4mul(T, pivi, M1);
    mat4mul(piv, M1, M2);
    mat4mul(rt_inv, M2, pose);

    #pragma unroll
    for (int i = 0; i < 3; ++i) {
        #pragma unroll
        for (int j = 0; j < 3; ++j) o->Rw[i*3+j] = pose[i*4+j];
        o->src[i] = pose[i*4+3];
    }
    #pragma unroll
    for (int i = 0; i < 9; ++i) o->kinv[i] = k_inv[i];
    o->sdd = sdd[0];
    #pragma unroll
    for (int i = 0; i < 3; ++i) { o->org[i] = origin[i]; o->invsp[i] = 1.f / spacing[i]; }
}

// ---------------------------------------------------------------------------
// Setup + z-slot mask kernel (runs FIRST). Thread 0 computes the pose;
// then all 256 threads mark which quad z-slices any ray can address:
// vz(i; u,v) = Az + Bz(u,v)*frac_i is linear in (u,v), so the 4 detector
// corners bound it. mask[z]=1 for z in [floor(min)-1, floor(max)+1].
// Only ~70 of 256 slices get marked (z advances ~4 voxels/step).
// ---------------------------------------------------------------------------
__global__ __launch_bounds__(256) void setup_kernel2(
    const float* __restrict__ rt_inv, const float* __restrict__ k_inv,
    const float* __restrict__ sdd, const float* __restrict__ isocenter,
    const float* __restrict__ origin, const float* __restrict__ spacing,
    const float* __restrict__ rot, const float* __restrict__ xyz,
    SetupOut* __restrict__ sp, unsigned char* __restrict__ gmask)
{
    __shared__ SetupOut S;
    if (threadIdx.x == 0) {
        compute_setup(rt_inv, k_inv, sdd, isocenter, origin, spacing, rot, xyz, &S);
        *sp = S;
    }
    __syncthreads();
    if (!gmask) return;

    __shared__ unsigned char m[256];
    m[threadIdx.x] = 0;
    __syncthreads();
    {
        const int i = threadIdx.x;
        const float frac = ((float)i + 0.5f) * (1.0f / (float)NSTEPS);
        const float Az = (S.src[2] - S.org[2]) * S.invsp[2];
        float vmin = 1e30f, vmax = -1e30f;
        #pragma unroll
        for (int c = 0; c < 4; ++c) {
            const float u = (c & 1)  ? ((float)W - 0.5f) : 0.5f;
            const float v = (c >> 1) ? ((float)H - 0.5f) : 0.5f;
            const float dcx = (S.kinv[0]*u + S.kinv[1]*v + S.kinv[2]) * S.sdd;
            const float dcy = (S.kinv[3]*u + S.kinv[4]*v + S.kinv[5]) * S.sdd;
            const float dcz = (S.kinv[6]*u + S.kinv[7]*v + S.kinv[8]) * S.sdd;
            const float dz  = S.Rw[6]*dcx + S.Rw[7]*dcy + S.Rw[8]*dcz;
            const float Bz  = dz * S.invsp[2];
            const float vz  = fmaf(Bz, frac, Az);
            vmin = fminf(vmin, vz);
            vmax = fmaxf(vmax, vz);
        }
        const int zlo = max(0,     (int)floorf(vmin) - 1);
        const int zhi = min(D - 1, (int)floorf(vmax) + 1);
        for (int z = zlo; z <= zhi; ++z) m[z] = 1;   // same-value races benign
    }
    __syncthreads();
    gmask[threadIdx.x] = m[threadIdx.x];
}

// ---------------------------------------------------------------------------
// Transposed QUAD repack, half2-staged, z-slot MASKED writes:
// ws layout [x][z][y] (y fastest), 8B element e=(x<<16)+(z<<8)+y packing
// fp16 { v(y,z), v(y,z+1c), v(y+1c,z), v(y+1c,z+1c) }.
// Unmasked z-slices are never written (never read under inside=true; the
// masked accumulate is a cndmask so garbage/poison can't propagate).
// Writes drop 128MB -> ~35MB.
// ---------------------------------------------------------------------------
__global__ __launch_bounds__(256) void repack_quad_h(const float* __restrict__ vol,
                                                     uint2* __restrict__ ws,
                                                     const unsigned char* __restrict__ gmask) {
    const int x  = blockIdx.x;
    const int y0 = blockIdx.y * 128;
    const int z0 = blockIdx.z * 64;
    const int tid  = threadIdx.x;

    __shared__ unsigned int  tf2[129 * 32];   // half2 z-pairs, XOR-swizzled
    __shared__ unsigned short halo_h[129];    // z-halo (z = z0+64, clamped)
    __shared__ unsigned char zm[64];          // write-mask for this z-tile
    const int xbase = x << 16;
    const int zh = min(z0 + 64, D - 1);

    if (tid < 64) zm[tid] = gmask ? gmask[z0 + tid] : (unsigned char)1;

    // Phase 1: rows of 64 z as 32 float2 loads (256B/row, coalesced)
    {
        const int s  = tid & 31;       // z-pair within row
        const int r0 = tid >> 5;       // 8 rows per pass
        for (int r = r0; r <= 128; r += 8) {
            const int y = min(y0 + r, D - 1);
            const float2 f = reinterpret_cast<const float2*>(vol + xbase + (y << 8) + z0)[s];
            __half2 h = __floats2half2_rn(f.x, f.y);
            tf2[r * 32 + (s ^ (r & 31))] = *reinterpret_cast<unsigned int*>(&h);
        }
        if (tid <= 128) {
            const int y = min(y0 + tid, D - 1);
            __half hh = __float2half_rn(vol[xbase + (y << 8) + zh]);
            halo_h[tid] = *reinterpret_cast<unsigned short*>(&hh);
        }
    }
    __syncthreads();

    // Phase 2: per z-pair w' (z=2w', 2w'+1), rows in two 64-lane halves.
    // Skip entire pairs with no masked slice (wave-uniform branch).
    const int grp  = tid >> 6;         // 0..3
    const int lane = tid & 63;
    for (int wp = grp; wp < 32; wp += 4) {
        const bool we = zm[2 * wp] != 0;
        const bool wo = zm[2 * wp + 1] != 0;
        if (!(we | wo)) continue;
        #pragma unroll
        for (int h = 0; h < 2; ++h) {
            const int ly = lane + 64 * h;
            const unsigned int u0 = tf2[ly * 32 + (wp ^ (ly & 31))];           // {v(ly,2w'), v(ly,2w'+1)}
            const unsigned int u1 = tf2[(ly + 1) * 32 + (wp ^ ((ly + 1) & 31))];
            unsigned int c0, c1;                                               // v(*, 2w'+2)
            if (wp < 31) {
                c0 = tf2[ly * 32 + ((wp + 1) ^ (ly & 31))] & 0xffffu;
                c1 = tf2[(ly + 1) * 32 + ((wp + 1) ^ ((ly + 1) & 31))] & 0xffffu;
            } else {
                c0 = halo_h[ly];
                c1 = halo_h[ly + 1];
            }
            const int zeven = z0 + 2 * wp;
            if (we) {
                uint2 qe;
                qe.x = u0;                          // {v(y,z),   v(y,z+1)}
                qe.y = u1;                          // {v(y+1,z), v(y+1,z+1)}
                ws[xbase + (zeven << 8) + y0 + 64 * h + lane] = qe;     // 512B runs
            }
            if (wo) {
                uint2 qo;
                qo.x = (u0 >> 16) | (c0 << 16);     // {v(y,z+1), v(y,z+2)}
                qo.y = (u1 >> 16) | (c1 << 16);
                ws[xbase + ((zeven + 1) << 8) + y0 + 64 * h + lane] = qo;
            }
        }
    }
}

// ---------------------------------------------------------------------------
// Ray setup in voxel space: vox(frac) = A + B*frac
// ---------------------------------------------------------------------------
struct RayState {
    float Ax, Ay, Az, Bx, By, Bz, seglen;
    int imin, imax;
    bool any;
};

__device__ __forceinline__ RayState ray_setup(const SetupOut* S, int ix, int iy) {
    RayState r;
    const float u = (float)ix + 0.5f;
    const float v = (float)iy + 0.5f;
    const float dcx = (S->kinv[0]*u + S->kinv[1]*v + S->kinv[2]) * S->sdd;
    const float dcy = (S->kinv[3]*u + S->kinv[4]*v + S->kinv[5]) * S->sdd;
    const float dcz = (S->kinv[6]*u + S->kinv[7]*v + S->kinv[8]) * S->sdd;
    const float dx = S->Rw[0]*dcx + S->Rw[1]*dcy + S->Rw[2]*dcz;
    const float dy = S->Rw[3]*dcx + S->Rw[4]*dcy + S->Rw[5]*dcz;
    const float dz = S->Rw[6]*dcx + S->Rw[7]*dcy + S->Rw[8]*dcz;
    r.seglen = sqrtf(dx*dx + dy*dy + dz*dz) * (1.0f / (float)NSTEPS);
    r.Ax = (S->src[0] - S->org[0]) * S->invsp[0];
    r.Ay = (S->src[1] - S->org[1]) * S->invsp[1];
    r.Az = (S->src[2] - S->org[2]) * S->invsp[2];
    r.Bx = dx * S->invsp[0];
    r.By = dy * S->invsp[1];
    r.Bz = dz * S->invsp[2];

    float fmin = 0.f, fmax = 1.f;
    bool empty = false;
    const float aa[3] = { r.Ax, r.Ay, r.Az };
    const float bb[3] = { r.Bx, r.By, r.Bz };
    #pragma unroll
    for (int k = 0; k < 3; ++k) {
        if (fabsf(bb[k]) > 1e-12f) {
            const float rcp = 1.f / bb[k];
            const float t0 = (0.f - aa[k]) * rcp;
            const float t1 = (DM1 - aa[k]) * rcp;
            fmin = fmaxf(fmin, fminf(t0, t1));
            fmax = fminf(fmax, fmaxf(t0, t1));
        } else if (aa[k] < 0.f || aa[k] > DM1) {
            empty = true;
        }
    }
    r.any = !empty && (fmax >= fmin);
    r.imin = max(0,          (int)floorf(fmin * (float)NSTEPS - 0.5f) - 1);
    r.imax = min(NSTEPS - 1, (int)ceilf (fmax * (float)NSTEPS - 0.5f) + 1);
    return r;
}

// ---------------------------------------------------------------------------
// Main raycast (unchanged from R9): setup via uniform s_loads, 4-way
// step-split, branchless inner loop, XCD-chunked swizzle.
// ---------------------------------------------------------------------------
__global__ __launch_bounds__(256) void drr_quad_kernel(
    const uint2* __restrict__ wsq, const SetupOut* __restrict__ S,
    float* __restrict__ out)
{
    const int b   = blockIdx.x;
    const int xcd = b & 7;
    const int j   = b >> 3;                  // 0..511 within XCD
    const int uu  = xcd * 16 + (j & 15);     // u-tile 0..127
    const int vv  = j >> 4;                  // v-tile 0..31

    const int seg = threadIdx.x & 3;
    const int iy = vv * 16 + (threadIdx.x >> 2);   // v -> vox_y (fastest axis)
    const int ix = uu * 4  + threadIdx.y;          // u
    const RayState r = ray_setup(S, ix, iy);

    float acc = 0.f;
    if (r.any) {
        #pragma unroll 4
        for (int i = r.imin + seg; i <= r.imax; i += 4) {
            const float frac = ((float)i + 0.5f) * (1.0f / (float)NSTEPS);
            const float vx = fmaf(r.Bx, frac, r.Ax);
            const float vy = fmaf(r.By, frac, r.Ay);
            const float vz = fmaf(r.Bz, frac, r.Az);
            const bool inside = (vx >= 0.f) && (vx <= DM1) &&
                                (vy >= 0.f) && (vy <= DM1) &&
                                (vz >= 0.f) && (vz <= DM1);
            const float cx = fminf(fmaxf(vx, 0.f), DM1);
            const float cy = fminf(fmaxf(vy, 0.f), DM1);
            const float cz = fminf(fmaxf(vz, 0.f), DM1);
            const float px = floorf(cx), py = floorf(cy), pz = floorf(cz);
            const int x0 = (int)px, y0 = (int)py, z0 = (int)pz;   // in [0,255]
            const int x1 = min(x0 + 1, D - 1);
            const float fx = cx - px, fy = cy - py, fz = cz - pz;
            const float gx = 1.f - fx, gy = 1.f - fy, gz = 1.f - fz;

            const int e0 = (x0 << 16) + (z0 << 8) + y0;    // [x][z][y] layout
            const int e1 = e0 + ((x1 - x0) << 16);

            const uint2 q0 = wsq[e0];
            const uint2 q1 = wsq[e1];
            const float2 a0 = __half22float2(*reinterpret_cast<const __half2*>(&q0.x)); // y0: z0,z1
            const float2 a1 = __half22float2(*reinterpret_cast<const __half2*>(&q0.y)); // y1: z0,z1
            const float2 b0 = __half22float2(*reinterpret_cast<const __half2*>(&q1.x));
            const float2 b1 = __half22float2(*reinterpret_cast<const __half2*>(&q1.y));

            const float c00 = a0.x*gz + a0.y*fz;
            const float c01 = a1.x*gz + a1.y*fz;
            const float c10 = b0.x*gz + b0.y*fz;
            const float c11 = b1.x*gz + b1.y*fz;
            const float samp = (c00*gy + c01*fy)*gx + (c10*gy + c11*fy)*fx;
            acc += inside ? samp : 0.f;   // cndmask: garbage in unwritten slots can't propagate
        }
    }
    acc += __shfl_xor(acc, 1);
    acc += __shfl_xor(acc, 2);
    if (seg == 0)
        out[iy * W + ix] = acc * r.seglen;
}

// ---------------------------------------------------------------------------
// Fallback: direct 8-gather path with inline setup (ws too small)
// ---------------------------------------------------------------------------
__global__ __launch_bounds__(256) void drr_direct_kernel(
    const float* __restrict__ vol,
    const float* __restrict__ rt_inv, const float* __restrict__ k_inv,
    const float* __restrict__ sdd, const float* __restrict__ isocenter,
    const float* __restrict__ origin, const float* __restrict__ spacing,
    const float* __restrict__ rot, const float* __restrict__ xyz,
    float* __restrict__ out)
{
    __shared__ SetupOut S;
    if (threadIdx.x == 0 && threadIdx.y == 0)
        compute_setup(rt_inv, k_inv, sdd, isocenter, origin, spacing, rot, xyz, &S);
    __syncthreads();

    const int seg = threadIdx.x & 1;
    const int iy = blockIdx.x * 32 + (threadIdx.x >> 1);
    const int ix = blockIdx.y * 4  + threadIdx.y;
    const RayState r = ray_setup(&S, ix, iy);

    float acc = 0.f;
    if (r.any) {
        #pragma unroll 4
        for (int i = r.imin + seg; i <= r.imax; i += 2) {
            const float frac = ((float)i + 0.5f) * (1.0f / (float)NSTEPS);
            const float vx = fmaf(r.Bx, frac, r.Ax);
            const float vy = fmaf(r.By, frac, r.Ay);
            const float vz = fmaf(r.Bz, frac, r.Az);
            const bool inside = (vx >= 0.f) && (vx <= DM1) &&
                                (vy >= 0.f) && (vy <= DM1) &&
                                (vz >= 0.f) && (vz <= DM1);
            const float cx = fminf(fmaxf(vx, 0.f), DM1);
            const float cy = fminf(fmaxf(vy, 0.f), DM1);
            const float cz = fminf(fmaxf(vz, 0.f), DM1);
            const float px = floorf(cx), py = floorf(cy), pz = floorf(cz);
            const int x0 = (int)px, y0 = (int)py, z0 = (int)pz;
            const int x1 = min(x0 + 1, D - 1);
            const int y1 = min(y0 + 1, D - 1);
            const int z1 = min(z0 + 1, D - 1);
            const float fx = cx - px, fy = cy - py, fz = cz - pz;
            const float gx = 1.f - fx, gy = 1.f - fy, gz = 1.f - fz;

            const int base = (x0 << 16) + (y0 << 8);
            const int bx = (x1 - x0) << 16;
            const int by = (y1 - y0) << 8;

            const float v000 = vol[base + z0],           v001 = vol[base + z1];
            const float v010 = vol[base + by + z0],      v011 = vol[base + by + z1];
            const float v100 = vol[base + bx + z0],      v101 = vol[base + bx + z1];
            const float v110 = vol[base + bx + by + z0], v111 = vol[base + bx + by + z1];

            const float c00 = v000*gz + v001*fz;
            const float c01 = v010*gz + v011*fz;
            const float c10 = v100*gz + v101*fz;
            const float c11 = v110*gz + v111*fz;
            const float samp = (c00*gy + c01*fy)*gx + (c10*gy + c11*fy)*fx;
            acc += inside ? samp : 0.f;
        }
    }
    acc += __shfl_xor(acc, 1);
    if (seg == 0)
        out[iy * W + ix] = acc * r.seglen;
}

extern "C" void kernel_launch(void* const* d_in, const int* in_sizes, int n_in,
                              void* d_out, int out_size, void* d_ws, size_t ws_size,
                              hipStream_t stream) {
    const float* vol      = (const float*)d_in[0];
    const float* rt_inv   = (const float*)d_in[1];
    const float* k_inv    = (const float*)d_in[2];
    const float* sdd      = (const float*)d_in[3];
    const float* iso      = (const float*)d_in[4];
    const float* origin   = (const float*)d_in[5];
    const float* spacing  = (const float*)d_in[6];
    const float* rot      = (const float*)d_in[7];
    const float* xyz      = (const float*)d_in[8];
    float* out = (float*)d_out;

    if (ws_size >= QUAD_WS_BYTES + 4096) {
        // masked path: setup+mask first, then masked repack, then raycast
        uint2* wsq = (uint2*)d_ws;
        SetupOut* sp = (SetupOut*)((char*)d_ws + QUAD_WS_BYTES);
        unsigned char* gmask = (unsigned char*)d_ws + QUAD_WS_BYTES + 512;

        setup_kernel2<<<1, 256, 0, stream>>>(rt_inv, k_inv, sdd, iso, origin,
                                             spacing, rot, xyz, sp, gmask);
        repack_quad_h<<<dim3(D, 2, 4), 256, 0, stream>>>(vol, wsq, gmask);
        drr_quad_kernel<<<dim3(4096), dim3(64, 4), 0, stream>>>(wsq, sp, out);
    } else if (ws_size >= QUAD_WS_BYTES) {
        // R9 fallback: unmasked repack; SetupOut steals last 128B of quad region
        uint2* wsq = (uint2*)d_ws;
        SetupOut* sp = (SetupOut*)((char*)d_ws + (QUAD_WS_BYTES - 128));

        repack_quad_h<<<dim3(D, 2, 4), 256, 0, stream>>>(vol, wsq, nullptr);
        setup_kernel2<<<1, 256, 0, stream>>>(rt_inv, k_inv, sdd, iso, origin,
                                             spacing, rot, xyz, sp, nullptr);
        drr_quad_kernel<<<dim3(4096), dim3(64, 4), 0, stream>>>(wsq, sp, out);
    } else {
        drr_direct_kernel<<<dim3(H / 32, W / 4), dim3(64, 4), 0, stream>>>(
            vol, rt_inv, k_inv, sdd, iso, origin, spacing, rot, xyz, out);
    }
}

// Round 12
// 64.556 us; speedup vs baseline: 1.0110x; 1.0110x over previous
//
#include <hip/hip_runtime.h>
#include <hip/hip_fp16.h>

#define W 512
#define H 512
#define NSTEPS 256
#define D 256
#define DM1 255.0f
#define QUAD_WS_BYTES (256ull*256ull*256ull*8ull)   // 128 MB fp16-quad volume

struct SetupOut {
    float Rw[9];
    float src[3];
    float kinv[9];
    float sdd;
    float org[3];
    float invsp[3];
};

__device__ __forceinline__ void mat4mul(const float* A, const float* B, float* C) {
    #pragma unroll
    for (int i = 0; i < 4; ++i)
        #pragma unroll
        for (int j = 0; j < 4; ++j) {
            float s = 0.f;
            #pragma unroll
            for (int k = 0; k < 4; ++k) s += A[i*4+k] * B[k*4+j];
            C[i*4+j] = s;
        }
}

__device__ void compute_setup(const float* rt_inv, const float* k_inv, const float* sdd,
                              const float* isocenter, const float* origin, const float* spacing,
                              const float* rot, const float* xyz, SetupOut* o) {
    // --- so3_exp_map ---
    float wx = rot[0], wy = rot[1], wz = rot[2];
    float th2 = wx*wx + wy*wy + wz*wz;
    float th = sqrtf(th2 + 1e-30f);
    float a, b;
    if (th2 > 1e-8f) { a = sinf(th) / th; b = (1.f - cosf(th)) / th2; }
    else             { a = 1.f - th2 / 6.f; b = 0.5f - th2 / 24.f; }
    float K[9]  = {0.f,-wz,wy,  wz,0.f,-wx,  -wy,wx,0.f};
    float K2[9];
    #pragma unroll
    for (int i = 0; i < 3; ++i)
        #pragma unroll
        for (int j = 0; j < 3; ++j) {
            float s = 0.f;
            #pragma unroll
            for (int k = 0; k < 3; ++k) s += K[i*3+k] * K[k*3+j];
            K2[i*3+j] = s;
        }
    float R[9];
    #pragma unroll
    for (int i = 0; i < 9; ++i) R[i] = ((i % 4 == 0) ? 1.f : 0.f) + a*K[i] + b*K2[i];
    float t[3];
    #pragma unroll
    for (int i = 0; i < 3; ++i)
        t[i] = R[i*3+0]*xyz[0] + R[i*3+1]*xyz[1] + R[i*3+2]*xyz[2];

    // --- inv(rtm) via Gauss-Jordan with partial pivoting ---
    float A[16], Ainv[16];
    #pragma unroll
    for (int i = 0; i < 16; ++i) { A[i] = rt_inv[i]; Ainv[i] = 0.f; }
    Ainv[0] = Ainv[5] = Ainv[10] = Ainv[15] = 1.f;
    for (int c = 0; c < 4; ++c) {
        int p = c; float mx = fabsf(A[c*4+c]);
        for (int r = c+1; r < 4; ++r) { float v = fabsf(A[r*4+c]); if (v > mx) { mx = v; p = r; } }
        if (p != c) {
            for (int j = 0; j < 4; ++j) {
                float tmp = A[c*4+j];   A[c*4+j]   = A[p*4+j];   A[p*4+j]   = tmp;
                tmp = Ainv[c*4+j];      Ainv[c*4+j] = Ainv[p*4+j]; Ainv[p*4+j] = tmp;
            }
        }
        float inv = 1.f / A[c*4+c];
        for (int j = 0; j < 4; ++j) { A[c*4+j] *= inv; Ainv[c*4+j] *= inv; }
        for (int r = 0; r < 4; ++r) if (r != c) {
            float f = A[r*4+c];
            for (int j = 0; j < 4; ++j) { A[r*4+j] -= f*A[c*4+j]; Ainv[r*4+j] -= f*Ainv[c*4+j]; }
        }
    }
    float cv[3];
    #pragma unroll
    for (int i = 0; i < 3; ++i)
        cv[i] = Ainv[i*4+0]*isocenter[0] + Ainv[i*4+1]*isocenter[1]
              + Ainv[i*4+2]*isocenter[2] + Ainv[i*4+3];

    // --- pose = rtm @ (piv @ (T @ piv_inv)) ---
    float T[16]    = {R[0],R[1],R[2],t[0],  R[3],R[4],R[5],t[1],  R[6],R[7],R[8],t[2],  0,0,0,1};
    float piv[16]  = {1,0,0, cv[0],  0,1,0, cv[1],  0,0,1, cv[2],  0,0,0,1};
    float pivi[16] = {1,0,0,-cv[0],  0,1,0,-cv[1],  0,0,1,-cv[2],  0,0,0,1};
    float M1[16], M2[16], pose[16];
    mat4mul(T, pivi, M1);
    mat4mul(piv, M1, M2);
    mat4mul(rt_inv, M2, pose);

    #pragma unroll
    for (int i = 0; i < 3; ++i) {
        #pragma unroll
        for (int j = 0; j < 3; ++j) o->Rw[i*3+j] = pose[i*4+j];
        o->src[i] = pose[i*4+3];
    }
    #pragma unroll
    for (int i = 0; i < 9; ++i) o->kinv[i] = k_inv[i];
    o->sdd = sdd[0];
    #pragma unroll
    for (int i = 0; i < 3; ++i) { o->org[i] = origin[i]; o->invsp[i] = 1.f / spacing[i]; }
}

// ---------------------------------------------------------------------------
// Setup + TIGHT z-slot mask kernel (runs FIRST). Thread 0 computes the pose;
// then all 256 threads mark which quad z-slices any ray can address.
// vz(i; u,v) is linear in (u,v) -> 4 detector corners bound it; eps=0.05
// absorbs corner-vs-ray fp divergence (bounded ~1e-3 voxel). Marks
// [floor(vmin-eps), floor(vmax+eps)+1] -- exactly the {z0, z0+1} read set.
// vz is point-like across the detector (dcz = sdd const), so ~2 slices/step
// -> ~130/256 slices marked (loose R11 mask marked ~192).
// ---------------------------------------------------------------------------
__global__ __launch_bounds__(256) void setup_kernel2(
    const float* __restrict__ rt_inv, const float* __restrict__ k_inv,
    const float* __restrict__ sdd, const float* __restrict__ isocenter,
    const float* __restrict__ origin, const float* __restrict__ spacing,
    const float* __restrict__ rot, const float* __restrict__ xyz,
    SetupOut* __restrict__ sp, unsigned char* __restrict__ gmask)
{
    __shared__ SetupOut S;
    if (threadIdx.x == 0) {
        compute_setup(rt_inv, k_inv, sdd, isocenter, origin, spacing, rot, xyz, &S);
        *sp = S;
    }
    __syncthreads();
    if (!gmask) return;

    __shared__ unsigned char m[256];
    m[threadIdx.x] = 0;
    __syncthreads();
    {
        const int i = threadIdx.x;
        const float frac = ((float)i + 0.5f) * (1.0f / (float)NSTEPS);
        const float Az = (S.src[2] - S.org[2]) * S.invsp[2];
        float vmin = 1e30f, vmax = -1e30f;
        #pragma unroll
        for (int c = 0; c < 4; ++c) {
            const float u = (c & 1)  ? ((float)W - 0.5f) : 0.5f;
            const float v = (c >> 1) ? ((float)H - 0.5f) : 0.5f;
            const float dcx = (S.kinv[0]*u + S.kinv[1]*v + S.kinv[2]) * S.sdd;
            const float dcy = (S.kinv[3]*u + S.kinv[4]*v + S.kinv[5]) * S.sdd;
            const float dcz = (S.kinv[6]*u + S.kinv[7]*v + S.kinv[8]) * S.sdd;
            const float dz  = S.Rw[6]*dcx + S.Rw[7]*dcy + S.Rw[8]*dcz;
            const float Bz  = dz * S.invsp[2];
            const float vz  = fmaf(Bz, frac, Az);
            vmin = fminf(vmin, vz);
            vmax = fmaxf(vmax, vz);
        }
        const int zlo = max(0,     (int)floorf(vmin - 0.05f));
        const int zhi = min(D - 1, (int)floorf(vmax + 0.05f) + 1);
        for (int z = zlo; z <= zhi; ++z) m[z] = 1;   // same-value races benign
    }
    __syncthreads();
    gmask[threadIdx.x] = m[threadIdx.x];
}

// ---------------------------------------------------------------------------
// Transposed QUAD repack, half2-staged, tight-masked NONTEMPORAL writes:
// ws layout [x][z][y] (y fastest), 8B element e=(x<<16)+(z<<8)+y packing
// fp16 { v(y,z), v(y,z+1c), v(y+1c,z), v(y+1c,z+1c) }.
// nt stores: the 100MB quad is read back only ~17MB by main -- don't let the
// write stream evict the fp32 volume from L2/L3.
// ---------------------------------------------------------------------------
__global__ __launch_bounds__(256) void repack_quad_h(const float* __restrict__ vol,
                                                     uint2* __restrict__ ws,
                                                     const unsigned char* __restrict__ gmask) {
    const int x  = blockIdx.x;
    const int y0 = blockIdx.y * 128;
    const int z0 = blockIdx.z * 64;
    const int tid  = threadIdx.x;

    __shared__ unsigned int  tf2[129 * 32];   // half2 z-pairs, XOR-swizzled
    __shared__ unsigned short halo_h[129];    // z-halo (z = z0+64, clamped)
    __shared__ unsigned char zm[64];          // write-mask for this z-tile
    const int xbase = x << 16;
    const int zh = min(z0 + 64, D - 1);

    if (tid < 64) zm[tid] = gmask ? gmask[z0 + tid] : (unsigned char)1;

    // Phase 1: rows of 64 z as 32 float2 loads (256B/row, coalesced)
    {
        const int s  = tid & 31;       // z-pair within row
        const int r0 = tid >> 5;       // 8 rows per pass
        for (int r = r0; r <= 128; r += 8) {
            const int y = min(y0 + r, D - 1);
            const float2 f = reinterpret_cast<const float2*>(vol + xbase + (y << 8) + z0)[s];
            __half2 h = __floats2half2_rn(f.x, f.y);
            tf2[r * 32 + (s ^ (r & 31))] = *reinterpret_cast<unsigned int*>(&h);
        }
        if (tid <= 128) {
            const int y = min(y0 + tid, D - 1);
            __half hh = __float2half_rn(vol[xbase + (y << 8) + zh]);
            halo_h[tid] = *reinterpret_cast<unsigned short*>(&hh);
        }
    }
    __syncthreads();

    // Phase 2: per z-pair w' (z=2w', 2w'+1), rows in two 64-lane halves.
    // Skip entire pairs with no masked slice (wave-uniform branch).
    const int grp  = tid >> 6;         // 0..3
    const int lane = tid & 63;
    for (int wp = grp; wp < 32; wp += 4) {
        const bool we = zm[2 * wp] != 0;
        const bool wo = zm[2 * wp + 1] != 0;
        if (!(we | wo)) continue;
        #pragma unroll
        for (int h = 0; h < 2; ++h) {
            const int ly = lane + 64 * h;
            const unsigned int u0 = tf2[ly * 32 + (wp ^ (ly & 31))];           // {v(ly,2w'), v(ly,2w'+1)}
            const unsigned int u1 = tf2[(ly + 1) * 32 + (wp ^ ((ly + 1) & 31))];
            unsigned int c0, c1;                                               // v(*, 2w'+2)
            if (wp < 31) {
                c0 = tf2[ly * 32 + ((wp + 1) ^ (ly & 31))] & 0xffffu;
                c1 = tf2[(ly + 1) * 32 + ((wp + 1) ^ ((ly + 1) & 31))] & 0xffffu;
            } else {
                c0 = halo_h[ly];
                c1 = halo_h[ly + 1];
            }
            const int zeven = z0 + 2 * wp;
            if (we) {
                const unsigned long long q =
                    (unsigned long long)u0 | ((unsigned long long)u1 << 32);
                __builtin_nontemporal_store(
                    q, reinterpret_cast<unsigned long long*>(
                           ws + xbase + (zeven << 8) + y0 + 64 * h + lane));
            }
            if (wo) {
                const unsigned int o0 = (u0 >> 16) | (c0 << 16);   // {v(y,z+1), v(y,z+2)}
                const unsigned int o1 = (u1 >> 16) | (c1 << 16);
                const unsigned long long q =
                    (unsigned long long)o0 | ((unsigned long long)o1 << 32);
                __builtin_nontemporal_store(
                    q, reinterpret_cast<unsigned long long*>(
                           ws + xbase + ((zeven + 1) << 8) + y0 + 64 * h + lane));
            }
        }
    }
}

// ---------------------------------------------------------------------------
// Ray setup in voxel space: vox(frac) = A + B*frac
// ---------------------------------------------------------------------------
struct RayState {
    float Ax, Ay, Az, Bx, By, Bz, seglen;
    int imin, imax;
    bool any;
};

__device__ __forceinline__ RayState ray_setup(const SetupOut* S, int ix, int iy) {
    RayState r;
    const float u = (float)ix + 0.5f;
    const float v = (float)iy + 0.5f;
    const float dcx = (S->kinv[0]*u + S->kinv[1]*v + S->kinv[2]) * S->sdd;
    const float dcy = (S->kinv[3]*u + S->kinv[4]*v + S->kinv[5]) * S->sdd;
    const float dcz = (S->kinv[6]*u + S->kinv[7]*v + S->kinv[8]) * S->sdd;
    const float dx = S->Rw[0]*dcx + S->Rw[1]*dcy + S->Rw[2]*dcz;
    const float dy = S->Rw[3]*dcx + S->Rw[4]*dcy + S->Rw[5]*dcz;
    const float dz = S->Rw[6]*dcx + S->Rw[7]*dcy + S->Rw[8]*dcz;
    r.seglen = sqrtf(dx*dx + dy*dy + dz*dz) * (1.0f / (float)NSTEPS);
    r.Ax = (S->src[0] - S->org[0]) * S->invsp[0];
    r.Ay = (S->src[1] - S->org[1]) * S->invsp[1];
    r.Az = (S->src[2] - S->org[2]) * S->invsp[2];
    r.Bx = dx * S->invsp[0];
    r.By = dy * S->invsp[1];
    r.Bz = dz * S->invsp[2];

    float fmin = 0.f, fmax = 1.f;
    bool empty = false;
    const float aa[3] = { r.Ax, r.Ay, r.Az };
    const float bb[3] = { r.Bx, r.By, r.Bz };
    #pragma unroll
    for (int k = 0; k < 3; ++k) {
        if (fabsf(bb[k]) > 1e-12f) {
            const float rcp = 1.f / bb[k];
            const float t0 = (0.f - aa[k]) * rcp;
            const float t1 = (DM1 - aa[k]) * rcp;
            fmin = fmaxf(fmin, fminf(t0, t1));
            fmax = fminf(fmax, fmaxf(t0, t1));
        } else if (aa[k] < 0.f || aa[k] > DM1) {
            empty = true;
        }
    }
    r.any = !empty && (fmax >= fmin);
    r.imin = max(0,          (int)floorf(fmin * (float)NSTEPS - 0.5f) - 1);
    r.imax = min(NSTEPS - 1, (int)ceilf (fmax * (float)NSTEPS - 0.5f) + 1);
    return r;
}

// ---------------------------------------------------------------------------
// Main raycast (unchanged): setup via uniform s_loads, 4-way step-split,
// branchless inner loop, XCD-chunked swizzle.
// ---------------------------------------------------------------------------
__global__ __launch_bounds__(256) void drr_quad_kernel(
    const uint2* __restrict__ wsq, const SetupOut* __restrict__ S,
    float* __restrict__ out)
{
    const int b   = blockIdx.x;
    const int xcd = b & 7;
    const int j   = b >> 3;                  // 0..511 within XCD
    const int uu  = xcd * 16 + (j & 15);     // u-tile 0..127
    const int vv  = j >> 4;                  // v-tile 0..31

    const int seg = threadIdx.x & 3;
    const int iy = vv * 16 + (threadIdx.x >> 2);   // v -> vox_y (fastest axis)
    const int ix = uu * 4  + threadIdx.y;          // u
    const RayState r = ray_setup(S, ix, iy);

    float acc = 0.f;
    if (r.any) {
        #pragma unroll 4
        for (int i = r.imin + seg; i <= r.imax; i += 4) {
            const float frac = ((float)i + 0.5f) * (1.0f / (float)NSTEPS);
            const float vx = fmaf(r.Bx, frac, r.Ax);
            const float vy = fmaf(r.By, frac, r.Ay);
            const float vz = fmaf(r.Bz, frac, r.Az);
            const bool inside = (vx >= 0.f) && (vx <= DM1) &&
                                (vy >= 0.f) && (vy <= DM1) &&
                                (vz >= 0.f) && (vz <= DM1);
            const float cx = fminf(fmaxf(vx, 0.f), DM1);
            const float cy = fminf(fmaxf(vy, 0.f), DM1);
            const float cz = fminf(fmaxf(vz, 0.f), DM1);
            const float px = floorf(cx), py = floorf(cy), pz = floorf(cz);
            const int x0 = (int)px, y0 = (int)py, z0 = (int)pz;   // in [0,255]
            const int x1 = min(x0 + 1, D - 1);
            const float fx = cx - px, fy = cy - py, fz = cz - pz;
            const float gx = 1.f - fx, gy = 1.f - fy, gz = 1.f - fz;

            const int e0 = (x0 << 16) + (z0 << 8) + y0;    // [x][z][y] layout
            const int e1 = e0 + ((x1 - x0) << 16);

            const uint2 q0 = wsq[e0];
            const uint2 q1 = wsq[e1];
            const float2 a0 = __half22float2(*reinterpret_cast<const __half2*>(&q0.x)); // y0: z0,z1
            const float2 a1 = __half22float2(*reinterpret_cast<const __half2*>(&q0.y)); // y1: z0,z1
            const float2 b0 = __half22float2(*reinterpret_cast<const __half2*>(&q1.x));
            const float2 b1 = __half22float2(*reinterpret_cast<const __half2*>(&q1.y));

            const float c00 = a0.x*gz + a0.y*fz;
            const float c01 = a1.x*gz + a1.y*fz;
            const float c10 = b0.x*gz + b0.y*fz;
            const float c11 = b1.x*gz + b1.y*fz;
            const float samp = (c00*gy + c01*fy)*gx + (c10*gy + c11*fy)*fx;
            acc += inside ? samp : 0.f;   // cndmask: garbage in unwritten slots can't propagate
        }
    }
    acc += __shfl_xor(acc, 1);
    acc += __shfl_xor(acc, 2);
    if (seg == 0)
        out[iy * W + ix] = acc * r.seglen;
}

// ---------------------------------------------------------------------------
// Fallback: direct 8-gather path with inline setup (ws too small)
// ---------------------------------------------------------------------------
__global__ __launch_bounds__(256) void drr_direct_kernel(
    const float* __restrict__ vol,
    const float* __restrict__ rt_inv, const float* __restrict__ k_inv,
    const float* __restrict__ sdd, const float* __restrict__ isocenter,
    const float* __restrict__ origin, const float* __restrict__ spacing,
    const float* __restrict__ rot, const float* __restrict__ xyz,
    float* __restrict__ out)
{
    __shared__ SetupOut S;
    if (threadIdx.x == 0 && threadIdx.y == 0)
        compute_setup(rt_inv, k_inv, sdd, isocenter, origin, spacing, rot, xyz, &S);
    __syncthreads();

    const int seg = threadIdx.x & 1;
    const int iy = blockIdx.x * 32 + (threadIdx.x >> 1);
    const int ix = blockIdx.y * 4  + threadIdx.y;
    const RayState r = ray_setup(&S, ix, iy);

    float acc = 0.f;
    if (r.any) {
        #pragma unroll 4
        for (int i = r.imin + seg; i <= r.imax; i += 2) {
            const float frac = ((float)i + 0.5f) * (1.0f / (float)NSTEPS);
            const float vx = fmaf(r.Bx, frac, r.Ax);
            const float vy = fmaf(r.By, frac, r.Ay);
            const float vz = fmaf(r.Bz, frac, r.Az);
            const bool inside = (vx >= 0.f) && (vx <= DM1) &&
                                (vy >= 0.f) && (vy <= DM1) &&
                                (vz >= 0.f) && (vz <= DM1);
            const float cx = fminf(fmaxf(vx, 0.f), DM1);
            const float cy = fminf(fmaxf(vy, 0.f), DM1);
            const float cz = fminf(fmaxf(vz, 0.f), DM1);
            const float px = floorf(cx), py = floorf(cy), pz = floorf(cz);
            const int x0 = (int)px, y0 = (int)py, z0 = (int)pz;
            const int x1 = min(x0 + 1, D - 1);
            const int y1 = min(y0 + 1, D - 1);
            const int z1 = min(z0 + 1, D - 1);
            const float fx = cx - px, fy = cy - py, fz = cz - pz;
            const float gx = 1.f - fx, gy = 1.f - fy, gz = 1.f - fz;

            const int base = (x0 << 16) + (y0 << 8);
            const int bx = (x1 - x0) << 16;
            const int by = (y1 - y0) << 8;

            const float v000 = vol[base + z0],           v001 = vol[base + z1];
            const float v010 = vol[base + by + z0],      v011 = vol[base + by + z1];
            const float v100 = vol[base + bx + z0],      v101 = vol[base + bx + z1];
            const float v110 = vol[base + bx + by + z0], v111 = vol[base + bx + by + z1];

            const float c00 = v000*gz + v001*fz;
            const float c01 = v010*gz + v011*fz;
            const float c10 = v100*gz + v101*fz;
            const float c11 = v110*gz + v111*fz;
            const float samp = (c00*gy + c01*fy)*gx + (c10*gy + c11*fy)*fx;
            acc += inside ? samp : 0.f;
        }
    }
    acc += __shfl_xor(acc, 1);
    if (seg == 0)
        out[iy * W + ix] = acc * r.seglen;
}

extern "C" void kernel_launch(void* const* d_in, const int* in_sizes, int n_in,
                              void* d_out, int out_size, void* d_ws, size_t ws_size,
                              hipStream_t stream) {
    const float* vol      = (const float*)d_in[0];
    const float* rt_inv   = (const float*)d_in[1];
    const float* k_inv    = (const float*)d_in[2];
    const float* sdd      = (const float*)d_in[3];
    const float* iso      = (const float*)d_in[4];
    const float* origin   = (const float*)d_in[5];
    const float* spacing  = (const float*)d_in[6];
    const float* rot      = (const float*)d_in[7];
    const float* xyz      = (const float*)d_in[8];
    float* out = (float*)d_out;

    if (ws_size >= QUAD_WS_BYTES + 4096) {
        // masked path: setup+mask first, then masked repack, then raycast
        uint2* wsq = (uint2*)d_ws;
        SetupOut* sp = (SetupOut*)((char*)d_ws + QUAD_WS_BYTES);
        unsigned char* gmask = (unsigned char*)d_ws + QUAD_WS_BYTES + 512;

        setup_kernel2<<<1, 256, 0, stream>>>(rt_inv, k_inv, sdd, iso, origin,
                                             spacing, rot, xyz, sp, gmask);
        repack_quad_h<<<dim3(D, 2, 4), 256, 0, stream>>>(vol, wsq, gmask);
        drr_quad_kernel<<<dim3(4096), dim3(64, 4), 0, stream>>>(wsq, sp, out);
    } else if (ws_size >= QUAD_WS_BYTES) {
        // fallback: unmasked repack; SetupOut steals last 128B of quad region
        uint2* wsq = (uint2*)d_ws;
        SetupOut* sp = (SetupOut*)((char*)d_ws + (QUAD_WS_BYTES - 128));

        repack_quad_h<<<dim3(D, 2, 4), 256, 0, stream>>>(vol, wsq, nullptr);
        setup_kernel2<<<1, 256, 0, stream>>>(rt_inv, k_inv, sdd, iso, origin,
                                             spacing, rot, xyz, sp, nullptr);
        drr_quad_kernel<<<dim3(4096), dim3(64, 4), 0, stream>>>(wsq, sp, out);
    } else {
        drr_direct_kernel<<<dim3(H / 32, W / 4), dim3(64, 4), 0, stream>>>(
            vol, rt_inv, k_inv, sdd, iso, origin, spacing, rot, xyz, out);
    }
}

// Round 13
// 61.500 us; speedup vs baseline: 1.0612x; 1.0497x over previous
//
#include <hip/hip_runtime.h>
#include <hip/hip_fp16.h>

#define W 512
#define H 512
#define NSTEPS 256
#define D 256
#define DM1 255.0f
#define QUAD_WS_BYTES (256ull*256ull*256ull*8ull)   // 128 MB fp16-quad volume

struct SetupOut {
    float Rw[9];
    float src[3];
    float kinv[9];
    float sdd;
    float org[3];
    float invsp[3];
};

__device__ __forceinline__ void mat4mul(const float* A, const float* B, float* C) {
    #pragma unroll
    for (int i = 0; i < 4; ++i)
        #pragma unroll
        for (int j = 0; j < 4; ++j) {
            float s = 0.f;
            #pragma unroll
            for (int k = 0; k < 4; ++k) s += A[i*4+k] * B[k*4+j];
            C[i*4+j] = s;
        }
}

__device__ void compute_setup(const float* rt_inv, const float* k_inv, const float* sdd,
                              const float* isocenter, const float* origin, const float* spacing,
                              const float* rot, const float* xyz, SetupOut* o) {
    // --- so3_exp_map ---
    float wx = rot[0], wy = rot[1], wz = rot[2];
    float th2 = wx*wx + wy*wy + wz*wz;
    float th = sqrtf(th2 + 1e-30f);
    float a, b;
    if (th2 > 1e-8f) { a = sinf(th) / th; b = (1.f - cosf(th)) / th2; }
    else             { a = 1.f - th2 / 6.f; b = 0.5f - th2 / 24.f; }
    float K[9]  = {0.f,-wz,wy,  wz,0.f,-wx,  -wy,wx,0.f};
    float K2[9];
    #pragma unroll
    for (int i = 0; i < 3; ++i)
        #pragma unroll
        for (int j = 0; j < 3; ++j) {
            float s = 0.f;
            #pragma unroll
            for (int k = 0; k < 3; ++k) s += K[i*3+k] * K[k*3+j];
            K2[i*3+j] = s;
        }
    float R[9];
    #pragma unroll
    for (int i = 0; i < 9; ++i) R[i] = ((i % 4 == 0) ? 1.f : 0.f) + a*K[i] + b*K2[i];
    float t[3];
    #pragma unroll
    for (int i = 0; i < 3; ++i)
        t[i] = R[i*3+0]*xyz[0] + R[i*3+1]*xyz[1] + R[i*3+2]*xyz[2];

    // --- inv(rtm): closed-form affine fast path, GJ fallback ---
    float Ainv[16];
    const float* M = rt_inv;
    if (M[12] == 0.f && M[13] == 0.f && M[14] == 0.f && M[15] == 1.f) {
        const float r00=M[0],r01=M[1],r02=M[2],  r10=M[4],r11=M[5],r12=M[6],
                    r20=M[8],r21=M[9],r22=M[10];
        const float c00 = r11*r22 - r12*r21, c01 = r02*r21 - r01*r22, c02 = r01*r12 - r02*r11;
        const float c10 = r12*r20 - r10*r22, c11 = r00*r22 - r02*r20, c12 = r02*r10 - r00*r12;
        const float c20 = r10*r21 - r11*r20, c21 = r01*r20 - r00*r21, c22 = r00*r11 - r01*r10;
        const float det = r00*c00 + r01*c10 + r02*c20;
        const float id  = 1.f / det;
        const float tx = M[3], ty = M[7], tz = M[11];
        Ainv[0]=c00*id; Ainv[1]=c01*id; Ainv[2]=c02*id;
        Ainv[4]=c10*id; Ainv[5]=c11*id; Ainv[6]=c12*id;
        Ainv[8]=c20*id; Ainv[9]=c21*id; Ainv[10]=c22*id;
        Ainv[3]  = -(Ainv[0]*tx + Ainv[1]*ty + Ainv[2]*tz);
        Ainv[7]  = -(Ainv[4]*tx + Ainv[5]*ty + Ainv[6]*tz);
        Ainv[11] = -(Ainv[8]*tx + Ainv[9]*ty + Ainv[10]*tz);
        Ainv[12]=0.f; Ainv[13]=0.f; Ainv[14]=0.f; Ainv[15]=1.f;
    } else {
        float A[16];
        #pragma unroll
        for (int i = 0; i < 16; ++i) { A[i] = rt_inv[i]; Ainv[i] = 0.f; }
        Ainv[0] = Ainv[5] = Ainv[10] = Ainv[15] = 1.f;
        for (int c = 0; c < 4; ++c) {
            int p = c; float mx = fabsf(A[c*4+c]);
            for (int r = c+1; r < 4; ++r) { float v = fabsf(A[r*4+c]); if (v > mx) { mx = v; p = r; } }
            if (p != c) {
                for (int j = 0; j < 4; ++j) {
                    float tmp = A[c*4+j];   A[c*4+j]   = A[p*4+j];   A[p*4+j]   = tmp;
                    tmp = Ainv[c*4+j];      Ainv[c*4+j] = Ainv[p*4+j]; Ainv[p*4+j] = tmp;
                }
            }
            float inv = 1.f / A[c*4+c];
            for (int j = 0; j < 4; ++j) { A[c*4+j] *= inv; Ainv[c*4+j] *= inv; }
            for (int r = 0; r < 4; ++r) if (r != c) {
                float f = A[r*4+c];
                for (int j = 0; j < 4; ++j) { A[r*4+j] -= f*A[c*4+j]; Ainv[r*4+j] -= f*Ainv[c*4+j]; }
            }
        }
    }
    float cv[3];
    #pragma unroll
    for (int i = 0; i < 3; ++i)
        cv[i] = Ainv[i*4+0]*isocenter[0] + Ainv[i*4+1]*isocenter[1]
              + Ainv[i*4+2]*isocenter[2] + Ainv[i*4+3];

    // --- pose = rtm @ (piv @ (T @ piv_inv)) ---
    float T[16]    = {R[0],R[1],R[2],t[0],  R[3],R[4],R[5],t[1],  R[6],R[7],R[8],t[2],  0,0,0,1};
    float piv[16]  = {1,0,0, cv[0],  0,1,0, cv[1],  0,0,1, cv[2],  0,0,0,1};
    float pivi[16] = {1,0,0,-cv[0],  0,1,0,-cv[1],  0,0,1,-cv[2],  0,0,0,1};
    float M1[16], M2[16], pose[16];
    mat4mul(T, pivi, M1);
    mat4mul(piv, M1, M2);
    mat4mul(rt_inv, M2, pose);

    #pragma unroll
    for (int i = 0; i < 3; ++i) {
        #pragma unroll
        for (int j = 0; j < 3; ++j) o->Rw[i*3+j] = pose[i*4+j];
        o->src[i] = pose[i*4+3];
    }
    #pragma unroll
    for (int i = 0; i < 9; ++i) o->kinv[i] = k_inv[i];
    o->sdd = sdd[0];
    #pragma unroll
    for (int i = 0; i < 3; ++i) { o->org[i] = origin[i]; o->invsp[i] = 1.f / spacing[i]; }
}

// ---------------------------------------------------------------------------
// Setup + TIGHT z-slot mask kernel (runs FIRST).
// vz(i; u,v) is linear in (u,v) -> 4 detector corners bound it; eps=0.05
// absorbs corner-vs-ray fp divergence (bounded ~1e-3 voxel).
// ---------------------------------------------------------------------------
__global__ __launch_bounds__(256) void setup_kernel2(
    const float* __restrict__ rt_inv, const float* __restrict__ k_inv,
    const float* __restrict__ sdd, const float* __restrict__ isocenter,
    const float* __restrict__ origin, const float* __restrict__ spacing,
    const float* __restrict__ rot, const float* __restrict__ xyz,
    SetupOut* __restrict__ sp, unsigned char* __restrict__ gmask)
{
    __shared__ SetupOut S;
    if (threadIdx.x == 0) {
        compute_setup(rt_inv, k_inv, sdd, isocenter, origin, spacing, rot, xyz, &S);
        *sp = S;
    }
    __syncthreads();
    if (!gmask) return;

    __shared__ unsigned char m[256];
    m[threadIdx.x] = 0;
    __syncthreads();
    {
        const int i = threadIdx.x;
        const float frac = ((float)i + 0.5f) * (1.0f / (float)NSTEPS);
        const float Az = (S.src[2] - S.org[2]) * S.invsp[2];
        float vmin = 1e30f, vmax = -1e30f;
        #pragma unroll
        for (int c = 0; c < 4; ++c) {
            const float u = (c & 1)  ? ((float)W - 0.5f) : 0.5f;
            const float v = (c >> 1) ? ((float)H - 0.5f) : 0.5f;
            const float dcx = (S.kinv[0]*u + S.kinv[1]*v + S.kinv[2]) * S.sdd;
            const float dcy = (S.kinv[3]*u + S.kinv[4]*v + S.kinv[5]) * S.sdd;
            const float dcz = (S.kinv[6]*u + S.kinv[7]*v + S.kinv[8]) * S.sdd;
            const float dz  = S.Rw[6]*dcx + S.Rw[7]*dcy + S.Rw[8]*dcz;
            const float Bz  = dz * S.invsp[2];
            const float vz  = fmaf(Bz, frac, Az);
            vmin = fminf(vmin, vz);
            vmax = fmaxf(vmax, vz);
        }
        const int zlo = max(0,     (int)floorf(vmin - 0.05f));
        const int zhi = min(D - 1, (int)floorf(vmax + 0.05f) + 1);
        for (int z = zlo; z <= zhi; ++z) m[z] = 1;   // same-value races benign
    }
    __syncthreads();
    gmask[threadIdx.x] = m[threadIdx.x];
}

// ---------------------------------------------------------------------------
// Transposed QUAD repack, half2-staged, tight-masked, WIDE stores:
// ws layout [x][z][y] (y fastest), 8B element e=(x<<16)+(z<<8)+y packing
// fp16 { v(y,z), v(y,z+1c), v(y+1c,z), v(y+1c,z+1c) }.
// Phase 2: each lane emits TWO consecutive y-elements as one uint4 ->
// 64 lanes x 16B = 1KB contiguous per store instr (half the store count of
// R12). Plain stores (nt REVERTED: main's latency-bound reads want L2-warm
// quad data; R12 showed nt cancelled the mask gain).
// ---------------------------------------------------------------------------
__global__ __launch_bounds__(256) void repack_quad_h(const float* __restrict__ vol,
                                                     uint2* __restrict__ ws,
                                                     const unsigned char* __restrict__ gmask) {
    const int x  = blockIdx.x;
    const int y0 = blockIdx.y * 128;
    const int z0 = blockIdx.z * 64;
    const int tid  = threadIdx.x;

    __shared__ unsigned int  tf2[129 * 32];   // half2 z-pairs, XOR-swizzled
    __shared__ unsigned short halo_h[129];    // z-halo (z = z0+64, clamped)
    __shared__ unsigned char zm[64];          // write-mask for this z-tile
    const int xbase = x << 16;
    const int zh = min(z0 + 64, D - 1);

    if (tid < 64) zm[tid] = gmask ? gmask[z0 + tid] : (unsigned char)1;

    // Phase 1: rows of 64 z as 32 float2 loads (256B/row, coalesced)
    {
        const int s  = tid & 31;       // z-pair within row
        const int r0 = tid >> 5;       // 8 rows per pass
        for (int r = r0; r <= 128; r += 8) {
            const int y = min(y0 + r, D - 1);
            const float2 f = reinterpret_cast<const float2*>(vol + xbase + (y << 8) + z0)[s];
            __half2 h = __floats2half2_rn(f.x, f.y);
            tf2[r * 32 + (s ^ (r & 31))] = *reinterpret_cast<unsigned int*>(&h);
        }
        if (tid <= 128) {
            const int y = min(y0 + tid, D - 1);
            __half hh = __float2half_rn(vol[xbase + (y << 8) + zh]);
            halo_h[tid] = *reinterpret_cast<unsigned short*>(&hh);
        }
    }
    __syncthreads();

    // Phase 2: per z-pair wp (z = z0+2wp, +1). Lane l covers y = y0+2l and
    // y0+2l+1 (rows 2l, 2l+1, 2l+2; 2l+2 <= 128 for l <= 63). One uint4
    // (two 8B elements) per masked slice -> 1KB contiguous per wave store.
    const int grp  = tid >> 6;         // 0..3
    const int lane = tid & 63;
    const int ra = 2 * lane, rb = 2 * lane + 1, rc = 2 * lane + 2;
    for (int wp = grp; wp < 32; wp += 4) {
        const bool we = zm[2 * wp] != 0;
        const bool wo = zm[2 * wp + 1] != 0;
        if (!(we | wo)) continue;
        const unsigned int a = tf2[ra * 32 + (wp ^ (ra & 31))];   // {v(y,2wp), v(y,2wp+1)}
        const unsigned int b = tf2[rb * 32 + (wp ^ (rb & 31))];
        const unsigned int c = tf2[rc * 32 + (wp ^ (rc & 31))];
        const int zeven = z0 + 2 * wp;
        if (we) {
            uint4 q; q.x = a; q.y = b; q.z = b; q.w = c;   // elems y=2l, y=2l+1
            *reinterpret_cast<uint4*>(ws + xbase + (zeven << 8) + y0 + ra) = q;
        }
        if (wo) {
            unsigned int na, nb, nc;                        // lo16 of column wp+1 (z = 2wp+2)
            if (wp < 31) {
                na = tf2[ra * 32 + ((wp + 1) ^ (ra & 31))] & 0xffffu;
                nb = tf2[rb * 32 + ((wp + 1) ^ (rb & 31))] & 0xffffu;
                nc = tf2[rc * 32 + ((wp + 1) ^ (rc & 31))] & 0xffffu;
            } else {
                na = halo_h[ra]; nb = halo_h[rb]; nc = halo_h[rc];
            }
            uint4 q;
            q.x = (a >> 16) | (na << 16);
            q.y = (b >> 16) | (nb << 16);
            q.z = q.y;
            q.w = (c >> 16) | (nc << 16);
            *reinterpret_cast<uint4*>(ws + xbase + ((zeven + 1) << 8) + y0 + ra) = q;
        }
    }
}

// ---------------------------------------------------------------------------
// Ray setup in voxel space: vox(frac) = A + B*frac
// ---------------------------------------------------------------------------
struct RayState {
    float Ax, Ay, Az, Bx, By, Bz, seglen;
    int imin, imax;
    bool any;
};

__device__ __forceinline__ RayState ray_setup(const SetupOut* S, int ix, int iy) {
    RayState r;
    const float u = (float)ix + 0.5f;
    const float v = (float)iy + 0.5f;
    const float dcx = (S->kinv[0]*u + S->kinv[1]*v + S->kinv[2]) * S->sdd;
    const float dcy = (S->kinv[3]*u + S->kinv[4]*v + S->kinv[5]) * S->sdd;
    const float dcz = (S->kinv[6]*u + S->kinv[7]*v + S->kinv[8]) * S->sdd;
    const float dx = S->Rw[0]*dcx + S->Rw[1]*dcy + S->Rw[2]*dcz;
    const float dy = S->Rw[3]*dcx + S->Rw[4]*dcy + S->Rw[5]*dcz;
    const float dz = S->Rw[6]*dcx + S->Rw[7]*dcy + S->Rw[8]*dcz;
    r.seglen = sqrtf(dx*dx + dy*dy + dz*dz) * (1.0f / (float)NSTEPS);
    r.Ax = (S->src[0] - S->org[0]) * S->invsp[0];
    r.Ay = (S->src[1] - S->org[1]) * S->invsp[1];
    r.Az = (S->src[2] - S->org[2]) * S->invsp[2];
    r.Bx = dx * S->invsp[0];
    r.By = dy * S->invsp[1];
    r.Bz = dz * S->invsp[2];

    float fmin = 0.f, fmax = 1.f;
    bool empty = false;
    const float aa[3] = { r.Ax, r.Ay, r.Az };
    const float bb[3] = { r.Bx, r.By, r.Bz };
    #pragma unroll
    for (int k = 0; k < 3; ++k) {
        if (fabsf(bb[k]) > 1e-12f) {
            const float rcp = 1.f / bb[k];
            const float t0 = (0.f - aa[k]) * rcp;
            const float t1 = (DM1 - aa[k]) * rcp;
            fmin = fmaxf(fmin, fminf(t0, t1));
            fmax = fminf(fmax, fmaxf(t0, t1));
        } else if (aa[k] < 0.f || aa[k] > DM1) {
            empty = true;
        }
    }
    r.any = !empty && (fmax >= fmin);
    r.imin = max(0,          (int)floorf(fmin * (float)NSTEPS - 0.5f) - 1);
    r.imax = min(NSTEPS - 1, (int)ceilf (fmax * (float)NSTEPS - 0.5f) + 1);
    return r;
}

// ---------------------------------------------------------------------------
// Main raycast: setup via uniform s_loads, 4-way step-split, branchless
// inner loop, XCD-chunked swizzle. unroll 8 (was 4) for deeper load ILP.
// ---------------------------------------------------------------------------
__global__ __launch_bounds__(256) void drr_quad_kernel(
    const uint2* __restrict__ wsq, const SetupOut* __restrict__ S,
    float* __restrict__ out)
{
    const int b   = blockIdx.x;
    const int xcd = b & 7;
    const int j   = b >> 3;                  // 0..511 within XCD
    const int uu  = xcd * 16 + (j & 15);     // u-tile 0..127
    const int vv  = j >> 4;                  // v-tile 0..31

    const int seg = threadIdx.x & 3;
    const int iy = vv * 16 + (threadIdx.x >> 2);   // v -> vox_y (fastest axis)
    const int ix = uu * 4  + threadIdx.y;          // u
    const RayState r = ray_setup(S, ix, iy);

    float acc = 0.f;
    if (r.any) {
        #pragma unroll 8
        for (int i = r.imin + seg; i <= r.imax; i += 4) {
            const float frac = ((float)i + 0.5f) * (1.0f / (float)NSTEPS);
            const float vx = fmaf(r.Bx, frac, r.Ax);
            const float vy = fmaf(r.By, frac, r.Ay);
            const float vz = fmaf(r.Bz, frac, r.Az);
            const bool inside = (vx >= 0.f) && (vx <= DM1) &&
                                (vy >= 0.f) && (vy <= DM1) &&
                                (vz >= 0.f) && (vz <= DM1);
            const float cx = fminf(fmaxf(vx, 0.f), DM1);
            const float cy = fminf(fmaxf(vy, 0.f), DM1);
            const float cz = fminf(fmaxf(vz, 0.f), DM1);
            const float px = floorf(cx), py = floorf(cy), pz = floorf(cz);
            const int x0 = (int)px, y0 = (int)py, z0 = (int)pz;   // in [0,255]
            const int x1 = min(x0 + 1, D - 1);
            const float fx = cx - px, fy = cy - py, fz = cz - pz;
            const float gx = 1.f - fx, gy = 1.f - fy, gz = 1.f - fz;

            const int e0 = (x0 << 16) + (z0 << 8) + y0;    // [x][z][y] layout
            const int e1 = e0 + ((x1 - x0) << 16);

            const uint2 q0 = wsq[e0];
            const uint2 q1 = wsq[e1];
            const float2 a0 = __half22float2(*reinterpret_cast<const __half2*>(&q0.x)); // y0: z0,z1
            const float2 a1 = __half22float2(*reinterpret_cast<const __half2*>(&q0.y)); // y1: z0,z1
            const float2 b0 = __half22float2(*reinterpret_cast<const __half2*>(&q1.x));
            const float2 b1 = __half22float2(*reinterpret_cast<const __half2*>(&q1.y));

            const float c00 = a0.x*gz + a0.y*fz;
            const float c01 = a1.x*gz + a1.y*fz;
            const float c10 = b0.x*gz + b0.y*fz;
            const float c11 = b1.x*gz + b1.y*fz;
            const float samp = (c00*gy + c01*fy)*gx + (c10*gy + c11*fy)*fx;
            acc += inside ? samp : 0.f;   // cndmask: garbage in unwritten slots can't propagate
        }
    }
    acc += __shfl_xor(acc, 1);
    acc += __shfl_xor(acc, 2);
    if (seg == 0)
        out[iy * W + ix] = acc * r.seglen;
}

// ---------------------------------------------------------------------------
// Fallback: direct 8-gather path with inline setup (ws too small)
// ---------------------------------------------------------------------------
__global__ __launch_bounds__(256) void drr_direct_kernel(
    const float* __restrict__ vol,
    const float* __restrict__ rt_inv, const float* __restrict__ k_inv,
    const float* __restrict__ sdd, const float* __restrict__ isocenter,
    const float* __restrict__ origin, const float* __restrict__ spacing,
    const float* __restrict__ rot, const float* __restrict__ xyz,
    float* __restrict__ out)
{
    __shared__ SetupOut S;
    if (threadIdx.x == 0 && threadIdx.y == 0)
        compute_setup(rt_inv, k_inv, sdd, isocenter, origin, spacing, rot, xyz, &S);
    __syncthreads();

    const int seg = threadIdx.x & 1;
    const int iy = blockIdx.x * 32 + (threadIdx.x >> 1);
    const int ix = blockIdx.y * 4  + threadIdx.y;
    const RayState r = ray_setup(&S, ix, iy);

    float acc = 0.f;
    if (r.any) {
        #pragma unroll 4
        for (int i = r.imin + seg; i <= r.imax; i += 2) {
            const float frac = ((float)i + 0.5f) * (1.0f / (float)NSTEPS);
            const float vx = fmaf(r.Bx, frac, r.Ax);
            const float vy = fmaf(r.By, frac, r.Ay);
            const float vz = fmaf(r.Bz, frac, r.Az);
            const bool inside = (vx >= 0.f) && (vx <= DM1) &&
                                (vy >= 0.f) && (vy <= DM1) &&
                                (vz >= 0.f) && (vz <= DM1);
            const float cx = fminf(fmaxf(vx, 0.f), DM1);
            const float cy = fminf(fmaxf(vy, 0.f), DM1);
            const float cz = fminf(fmaxf(vz, 0.f), DM1);
            const float px = floorf(cx), py = floorf(cy), pz = floorf(cz);
            const int x0 = (int)px, y0 = (int)py, z0 = (int)pz;
            const int x1 = min(x0 + 1, D - 1);
            const int y1 = min(y0 + 1, D - 1);
            const int z1 = min(z0 + 1, D - 1);
            const float fx = cx - px, fy = cy - py, fz = cz - pz;
            const float gx = 1.f - fx, gy = 1.f - fy, gz = 1.f - fz;

            const int base = (x0 << 16) + (y0 << 8);
            const int bx = (x1 - x0) << 16;
            const int by = (y1 - y0) << 8;

            const float v000 = vol[base + z0],           v001 = vol[base + z1];
            const float v010 = vol[base + by + z0],      v011 = vol[base + by + z1];
            const float v100 = vol[base + bx + z0],      v101 = vol[base + bx + z1];
            const float v110 = vol[base + bx + by + z0], v111 = vol[base + bx + by + z1];

            const float c00 = v000*gz + v001*fz;
            const float c01 = v010*gz + v011*fz;
            const float c10 = v100*gz + v101*fz;
            const float c11 = v110*gz + v111*fz;
            const float samp = (c00*gy + c01*fy)*gx + (c10*gy + c11*fy)*fx;
            acc += inside ? samp : 0.f;
        }
    }
    acc += __shfl_xor(acc, 1);
    if (seg == 0)
        out[iy * W + ix] = acc * r.seglen;
}

extern "C" void kernel_launch(void* const* d_in, const int* in_sizes, int n_in,
                              void* d_out, int out_size, void* d_ws, size_t ws_size,
                              hipStream_t stream) {
    const float* vol      = (const float*)d_in[0];
    const float* rt_inv   = (const float*)d_in[1];
    const float* k_inv    = (const float*)d_in[2];
    const float* sdd      = (const float*)d_in[3];
    const float* iso      = (const float*)d_in[4];
    const float* origin   = (const float*)d_in[5];
    const float* spacing  = (const float*)d_in[6];
    const float* rot      = (const float*)d_in[7];
    const float* xyz      = (const float*)d_in[8];
    float* out = (float*)d_out;

    if (ws_size >= QUAD_WS_BYTES + 4096) {
        // masked path: setup+mask first, then masked repack, then raycast
        uint2* wsq = (uint2*)d_ws;
        SetupOut* sp = (SetupOut*)((char*)d_ws + QUAD_WS_BYTES);
        unsigned char* gmask = (unsigned char*)d_ws + QUAD_WS_BYTES + 512;

        setup_kernel2<<<1, 256, 0, stream>>>(rt_inv, k_inv, sdd, iso, origin,
                                             spacing, rot, xyz, sp, gmask);
        repack_quad_h<<<dim3(D, 2, 4), 256, 0, stream>>>(vol, wsq, gmask);
        drr_quad_kernel<<<dim3(4096), dim3(64, 4), 0, stream>>>(wsq, sp, out);
    } else if (ws_size >= QUAD_WS_BYTES) {
        // fallback: unmasked repack; SetupOut steals last 128B of quad region
        uint2* wsq = (uint2*)d_ws;
        SetupOut* sp = (SetupOut*)((char*)d_ws + (QUAD_WS_BYTES - 128));

        repack_quad_h<<<dim3(D, 2, 4), 256, 0, stream>>>(vol, wsq, nullptr);
        setup_kernel2<<<1, 256, 0, stream>>>(rt_inv, k_inv, sdd, iso, origin,
                                             spacing, rot, xyz, sp, nullptr);
        drr_quad_kernel<<<dim3(4096), dim3(64, 4), 0, stream>>>(wsq, sp, out);
    } else {
        drr_direct_kernel<<<dim3(H / 32, W / 4), dim3(64, 4), 0, stream>>>(
            vol, rt_inv, k_inv, sdd, iso, origin, spacing, rot, xyz, out);
    }
}

// Round 14
// 53.490 us; speedup vs baseline: 1.2201x; 1.1497x over previous
//
#include <hip/hip_runtime.h>
#include <hip/hip_fp16.h>

#define W 512
#define H 512
#define NSTEPS 256
#define D 256
#define DM1 255.0f
#define PAIR_WS_BYTES (256ull*256ull*256ull*4ull)   // 64 MB fp16 y-pair volume

struct SetupOut {
    float Rw[9];
    float src[3];
    float kinv[9];
    float sdd;
    float org[3];
    float invsp[3];
};

__device__ __forceinline__ void mat4mul(const float* A, const float* B, float* C) {
    #pragma unroll
    for (int i = 0; i < 4; ++i)
        #pragma unroll
        for (int j = 0; j < 4; ++j) {
            float s = 0.f;
            #pragma unroll
            for (int k = 0; k < 4; ++k) s += A[i*4+k] * B[k*4+j];
            C[i*4+j] = s;
        }
}

__device__ void compute_setup(const float* rt_inv, const float* k_inv, const float* sdd,
                              const float* isocenter, const float* origin, const float* spacing,
                              const float* rot, const float* xyz, SetupOut* o) {
    // --- so3_exp_map ---
    float wx = rot[0], wy = rot[1], wz = rot[2];
    float th2 = wx*wx + wy*wy + wz*wz;
    float th = sqrtf(th2 + 1e-30f);
    float a, b;
    if (th2 > 1e-8f) { a = sinf(th) / th; b = (1.f - cosf(th)) / th2; }
    else             { a = 1.f - th2 / 6.f; b = 0.5f - th2 / 24.f; }
    float K[9]  = {0.f,-wz,wy,  wz,0.f,-wx,  -wy,wx,0.f};
    float K2[9];
    #pragma unroll
    for (int i = 0; i < 3; ++i)
        #pragma unroll
        for (int j = 0; j < 3; ++j) {
            float s = 0.f;
            #pragma unroll
            for (int k = 0; k < 3; ++k) s += K[i*3+k] * K[k*3+j];
            K2[i*3+j] = s;
        }
    float R[9];
    #pragma unroll
    for (int i = 0; i < 9; ++i) R[i] = ((i % 4 == 0) ? 1.f : 0.f) + a*K[i] + b*K2[i];
    float t[3];
    #pragma unroll
    for (int i = 0; i < 3; ++i)
        t[i] = R[i*3+0]*xyz[0] + R[i*3+1]*xyz[1] + R[i*3+2]*xyz[2];

    // --- inv(rtm): closed-form affine fast path, GJ fallback ---
    float Ainv[16];
    const float* M = rt_inv;
    if (M[12] == 0.f && M[13] == 0.f && M[14] == 0.f && M[15] == 1.f) {
        const float r00=M[0],r01=M[1],r02=M[2],  r10=M[4],r11=M[5],r12=M[6],
                    r20=M[8],r21=M[9],r22=M[10];
        const float c00 = r11*r22 - r12*r21, c01 = r02*r21 - r01*r22, c02 = r01*r12 - r02*r11;
        const float c10 = r12*r20 - r10*r22, c11 = r00*r22 - r02*r20, c12 = r02*r10 - r00*r12;
        const float c20 = r10*r21 - r11*r20, c21 = r01*r20 - r00*r21, c22 = r00*r11 - r01*r10;
        const float det = r00*c00 + r01*c10 + r02*c20;
        const float id  = 1.f / det;
        const float tx = M[3], ty = M[7], tz = M[11];
        Ainv[0]=c00*id; Ainv[1]=c01*id; Ainv[2]=c02*id;
        Ainv[4]=c10*id; Ainv[5]=c11*id; Ainv[6]=c12*id;
        Ainv[8]=c20*id; Ainv[9]=c21*id; Ainv[10]=c22*id;
        Ainv[3]  = -(Ainv[0]*tx + Ainv[1]*ty + Ainv[2]*tz);
        Ainv[7]  = -(Ainv[4]*tx + Ainv[5]*ty + Ainv[6]*tz);
        Ainv[11] = -(Ainv[8]*tx + Ainv[9]*ty + Ainv[10]*tz);
        Ainv[12]=0.f; Ainv[13]=0.f; Ainv[14]=0.f; Ainv[15]=1.f;
    } else {
        float A[16];
        #pragma unroll
        for (int i = 0; i < 16; ++i) { A[i] = rt_inv[i]; Ainv[i] = 0.f; }
        Ainv[0] = Ainv[5] = Ainv[10] = Ainv[15] = 1.f;
        for (int c = 0; c < 4; ++c) {
            int p = c; float mx = fabsf(A[c*4+c]);
            for (int r = c+1; r < 4; ++r) { float v = fabsf(A[r*4+c]); if (v > mx) { mx = v; p = r; } }
            if (p != c) {
                for (int j = 0; j < 4; ++j) {
                    float tmp = A[c*4+j];   A[c*4+j]   = A[p*4+j];   A[p*4+j]   = tmp;
                    tmp = Ainv[c*4+j];      Ainv[c*4+j] = Ainv[p*4+j]; Ainv[p*4+j] = tmp;
                }
            }
            float inv = 1.f / A[c*4+c];
            for (int j = 0; j < 4; ++j) { A[c*4+j] *= inv; Ainv[c*4+j] *= inv; }
            for (int r = 0; r < 4; ++r) if (r != c) {
                float f = A[r*4+c];
                for (int j = 0; j < 4; ++j) { A[r*4+j] -= f*A[c*4+j]; Ainv[r*4+j] -= f*Ainv[c*4+j]; }
            }
        }
    }
    float cv[3];
    #pragma unroll
    for (int i = 0; i < 3; ++i)
        cv[i] = Ainv[i*4+0]*isocenter[0] + Ainv[i*4+1]*isocenter[1]
              + Ainv[i*4+2]*isocenter[2] + Ainv[i*4+3];

    // --- pose = rtm @ (piv @ (T @ piv_inv)) ---
    float T[16]    = {R[0],R[1],R[2],t[0],  R[3],R[4],R[5],t[1],  R[6],R[7],R[8],t[2],  0,0,0,1};
    float piv[16]  = {1,0,0, cv[0],  0,1,0, cv[1],  0,0,1, cv[2],  0,0,0,1};
    float pivi[16] = {1,0,0,-cv[0],  0,1,0,-cv[1],  0,0,1,-cv[2],  0,0,0,1};
    float M1[16], M2[16], pose[16];
    mat4mul(T, pivi, M1);
    mat4mul(piv, M1, M2);
    mat4mul(rt_inv, M2, pose);

    #pragma unroll
    for (int i = 0; i < 3; ++i) {
        #pragma unroll
        for (int j = 0; j < 3; ++j) o->Rw[i*3+j] = pose[i*4+j];
        o->src[i] = pose[i*4+3];
    }
    #pragma unroll
    for (int i = 0; i < 9; ++i) o->kinv[i] = k_inv[i];
    o->sdd = sdd[0];
    #pragma unroll
    for (int i = 0; i < 3; ++i) { o->org[i] = origin[i]; o->invsp[i] = 1.f / spacing[i]; }
}

// ---------------------------------------------------------------------------
// Setup + TIGHT z-slot mask kernel (runs FIRST).
// vz(i; u,v) is linear in (u,v) -> 4 detector corners bound it; eps=0.05
// absorbs corner-vs-ray fp divergence (bounded ~1e-3 voxel). Marks
// [floor(vmin-eps), floor(vmax+eps)+1] == the {z0, z0+1} read set per step.
// ---------------------------------------------------------------------------
__global__ __launch_bounds__(256) void setup_kernel2(
    const float* __restrict__ rt_inv, const float* __restrict__ k_inv,
    const float* __restrict__ sdd, const float* __restrict__ isocenter,
    const float* __restrict__ origin, const float* __restrict__ spacing,
    const float* __restrict__ rot, const float* __restrict__ xyz,
    SetupOut* __restrict__ sp, unsigned char* __restrict__ gmask)
{
    __shared__ SetupOut S;
    if (threadIdx.x == 0) {
        compute_setup(rt_inv, k_inv, sdd, isocenter, origin, spacing, rot, xyz, &S);
        *sp = S;
    }
    __syncthreads();
    if (!gmask) return;

    __shared__ unsigned char m[256];
    m[threadIdx.x] = 0;
    __syncthreads();
    {
        const int i = threadIdx.x;
        const float frac = ((float)i + 0.5f) * (1.0f / (float)NSTEPS);
        const float Az = (S.src[2] - S.org[2]) * S.invsp[2];
        float vmin = 1e30f, vmax = -1e30f;
        #pragma unroll
        for (int c = 0; c < 4; ++c) {
            const float u = (c & 1)  ? ((float)W - 0.5f) : 0.5f;
            const float v = (c >> 1) ? ((float)H - 0.5f) : 0.5f;
            const float dcx = (S.kinv[0]*u + S.kinv[1]*v + S.kinv[2]) * S.sdd;
            const float dcy = (S.kinv[3]*u + S.kinv[4]*v + S.kinv[5]) * S.sdd;
            const float dcz = (S.kinv[6]*u + S.kinv[7]*v + S.kinv[8]) * S.sdd;
            const float dz  = S.Rw[6]*dcx + S.Rw[7]*dcy + S.Rw[8]*dcz;
            const float Bz  = dz * S.invsp[2];
            const float vz  = fmaf(Bz, frac, Az);
            vmin = fminf(vmin, vz);
            vmax = fmaxf(vmax, vz);
        }
        const int zlo = max(0,     (int)floorf(vmin - 0.05f));
        const int zhi = min(D - 1, (int)floorf(vmax + 0.05f) + 1);
        for (int z = zlo; z <= zhi; ++z) m[z] = 1;   // same-value races benign
    }
    __syncthreads();
    gmask[threadIdx.x] = m[threadIdx.x];
}

// ---------------------------------------------------------------------------
// Transposed Y-PAIR repack, half2-staged, tight-masked:
// ws layout [x][z][y] (y fastest), 4B element e=(x<<16)+(z<<8)+y holding
// fp16 { v(x,y,z), v(x,y+1c,z) }. Half the write bytes of the quad format;
// main's line traffic is unchanged (R6: line-bound, not gather-instr-bound).
// Phase 1 identical to quad repack (fp32 rows -> half2 z-pair LDS tile).
// Phase 2: per masked z, lane l emits elements y=2l,2l+1 as one uint2
// (512B contiguous per wave-store).
// ---------------------------------------------------------------------------
__global__ __launch_bounds__(256) void repack_pair_t(const float* __restrict__ vol,
                                                     unsigned int* __restrict__ ws,
                                                     const unsigned char* __restrict__ gmask) {
    const int x  = blockIdx.x;
    const int y0 = blockIdx.y * 128;
    const int z0 = blockIdx.z * 64;
    const int tid  = threadIdx.x;

    __shared__ unsigned int tf2[129 * 32];    // half2 z-pairs, XOR-swizzled
    __shared__ unsigned char zm[64];          // write-mask for this z-tile
    const int xbase = x << 16;

    if (tid < 64) zm[tid] = gmask ? gmask[z0 + tid] : (unsigned char)1;

    // Phase 1: rows of 64 z as 32 float2 loads (256B/row, coalesced)
    {
        const int s  = tid & 31;       // z-pair within row
        const int r0 = tid >> 5;       // 8 rows per pass
        for (int r = r0; r <= 128; r += 8) {
            const int y = min(y0 + r, D - 1);
            const float2 f = reinterpret_cast<const float2*>(vol + xbase + (y << 8) + z0)[s];
            __half2 h = __floats2half2_rn(f.x, f.y);
            tf2[r * 32 + (s ^ (r & 31))] = *reinterpret_cast<unsigned int*>(&h);
        }
    }
    __syncthreads();

    // Phase 2: per masked z, lane l covers y=2l..2l+1 (rows 2l,2l+1,2l+2).
    const int grp  = tid >> 6;         // 0..3
    const int lane = tid & 63;
    const int ra = 2 * lane, rb = 2 * lane + 1, rc = 2 * lane + 2;
    for (int w = grp; w < 64; w += 4) {
        if (!zm[w]) continue;
        const int wp = w >> 1;
        const int sh = (w & 1) << 4;   // 0 for even z (lo half), 16 for odd
        const unsigned int ha = (tf2[ra * 32 + (wp ^ (ra & 31))] >> sh) & 0xffffu;
        const unsigned int hb = (tf2[rb * 32 + (wp ^ (rb & 31))] >> sh) & 0xffffu;
        const unsigned int hc = (tf2[rc * 32 + (wp ^ (rc & 31))] >> sh) & 0xffffu;
        uint2 q;
        q.x = ha | (hb << 16);         // elem y=2l:   {v(2l,z),   v(2l+1,z)}
        q.y = hb | (hc << 16);         // elem y=2l+1: {v(2l+1,z), v(2l+2,z)}
        *reinterpret_cast<uint2*>(ws + xbase + ((z0 + w) << 8) + y0 + ra) = q;
    }
}

// ---------------------------------------------------------------------------
// Ray setup in voxel space: vox(frac) = A + B*frac
// ---------------------------------------------------------------------------
struct RayState {
    float Ax, Ay, Az, Bx, By, Bz, seglen;
    int imin, imax;
    bool any;
};

__device__ __forceinline__ RayState ray_setup(const SetupOut* S, int ix, int iy) {
    RayState r;
    const float u = (float)ix + 0.5f;
    const float v = (float)iy + 0.5f;
    const float dcx = (S->kinv[0]*u + S->kinv[1]*v + S->kinv[2]) * S->sdd;
    const float dcy = (S->kinv[3]*u + S->kinv[4]*v + S->kinv[5]) * S->sdd;
    const float dcz = (S->kinv[6]*u + S->kinv[7]*v + S->kinv[8]) * S->sdd;
    const float dx = S->Rw[0]*dcx + S->Rw[1]*dcy + S->Rw[2]*dcz;
    const float dy = S->Rw[3]*dcx + S->Rw[4]*dcy + S->Rw[5]*dcz;
    const float dz = S->Rw[6]*dcx + S->Rw[7]*dcy + S->Rw[8]*dcz;
    r.seglen = sqrtf(dx*dx + dy*dy + dz*dz) * (1.0f / (float)NSTEPS);
    r.Ax = (S->src[0] - S->org[0]) * S->invsp[0];
    r.Ay = (S->src[1] - S->org[1]) * S->invsp[1];
    r.Az = (S->src[2] - S->org[2]) * S->invsp[2];
    r.Bx = dx * S->invsp[0];
    r.By = dy * S->invsp[1];
    r.Bz = dz * S->invsp[2];

    float fmin = 0.f, fmax = 1.f;
    bool empty = false;
    const float aa[3] = { r.Ax, r.Ay, r.Az };
    const float bb[3] = { r.Bx, r.By, r.Bz };
    #pragma unroll
    for (int k = 0; k < 3; ++k) {
        if (fabsf(bb[k]) > 1e-12f) {
            const float rcp = 1.f / bb[k];
            const float t0 = (0.f - aa[k]) * rcp;
            const float t1 = (DM1 - aa[k]) * rcp;
            fmin = fmaxf(fmin, fminf(t0, t1));
            fmax = fminf(fmax, fmaxf(t0, t1));
        } else if (aa[k] < 0.f || aa[k] > DM1) {
            empty = true;
        }
    }
    r.any = !empty && (fmax >= fmin);
    r.imin = max(0,          (int)floorf(fmin * (float)NSTEPS - 0.5f) - 1);
    r.imax = min(NSTEPS - 1, (int)ceilf (fmax * (float)NSTEPS - 0.5f) + 1);
    return r;
}

// ---------------------------------------------------------------------------
// Main raycast over transposed fp16 y-pair volume: 4 near-coalesced dword
// gathers/sample (same line traffic as the 2-gather quad; R6 established
// line-bound). Branchless, 4-way step-split, XCD-chunked swizzle,
// setup via uniform s_loads.
// ---------------------------------------------------------------------------
__global__ __launch_bounds__(256) void drr_pair_kernel(
    const unsigned int* __restrict__ wsp, const SetupOut* __restrict__ S,
    float* __restrict__ out)
{
    const int b   = blockIdx.x;
    const int xcd = b & 7;
    const int j   = b >> 3;                  // 0..511 within XCD
    const int uu  = xcd * 16 + (j & 15);     // u-tile 0..127
    const int vv  = j >> 4;                  // v-tile 0..31

    const int seg = threadIdx.x & 3;
    const int iy = vv * 16 + (threadIdx.x >> 2);   // v -> vox_y (fastest axis)
    const int ix = uu * 4  + threadIdx.y;          // u
    const RayState r = ray_setup(S, ix, iy);

    float acc = 0.f;
    if (r.any) {
        #pragma unroll 4
        for (int i = r.imin + seg; i <= r.imax; i += 4) {
            const float frac = ((float)i + 0.5f) * (1.0f / (float)NSTEPS);
            const float vx = fmaf(r.Bx, frac, r.Ax);
            const float vy = fmaf(r.By, frac, r.Ay);
            const float vz = fmaf(r.Bz, frac, r.Az);
            const bool inside = (vx >= 0.f) && (vx <= DM1) &&
                                (vy >= 0.f) && (vy <= DM1) &&
                                (vz >= 0.f) && (vz <= DM1);
            const float cx = fminf(fmaxf(vx, 0.f), DM1);
            const float cy = fminf(fmaxf(vy, 0.f), DM1);
            const float cz = fminf(fmaxf(vz, 0.f), DM1);
            const float px = floorf(cx), py = floorf(cy), pz = floorf(cz);
            const int x0 = (int)px, y0 = (int)py, z0 = (int)pz;   // in [0,255]
            const int x1 = min(x0 + 1, D - 1);
            const int z1 = min(z0 + 1, D - 1);
            const float fx = cx - px, fy = cy - py, fz = cz - pz;
            const float gx = 1.f - fx, gy = 1.f - fy, gz = 1.f - fz;

            const int e00 = (x0 << 16) + (z0 << 8) + y0;   // [x][z][y] layout
            const int zo  = (z1 - z0) << 8;
            const int xo  = (x1 - x0) << 16;

            const unsigned int q00 = wsp[e00];
            const unsigned int q01 = wsp[e00 + zo];
            const unsigned int q10 = wsp[e00 + xo];
            const unsigned int q11 = wsp[e00 + xo + zo];

            const float2 a00 = __half22float2(*reinterpret_cast<const __half2*>(&q00)); // (x0,z0): y0,y1
            const float2 a01 = __half22float2(*reinterpret_cast<const __half2*>(&q01)); // (x0,z1)
            const float2 a10 = __half22float2(*reinterpret_cast<const __half2*>(&q10)); // (x1,z0)
            const float2 a11 = __half22float2(*reinterpret_cast<const __half2*>(&q11)); // (x1,z1)

            // y-interp, then z, then x
            const float m00 = a00.x*gy + a00.y*fy;
            const float m01 = a01.x*gy + a01.y*fy;
            const float m10 = a10.x*gy + a10.y*fy;
            const float m11 = a11.x*gy + a11.y*fy;
            const float c0 = m00*gz + m01*fz;
            const float c1 = m10*gz + m11*fz;
            const float samp = c0*gx + c1*fx;
            acc += inside ? samp : 0.f;   // cndmask: unwritten slots can't propagate
        }
    }
    acc += __shfl_xor(acc, 1);
    acc += __shfl_xor(acc, 2);
    if (seg == 0)
        out[iy * W + ix] = acc * r.seglen;
}

// ---------------------------------------------------------------------------
// Fallback: direct 8-gather path with inline setup (ws too small)
// ---------------------------------------------------------------------------
__global__ __launch_bounds__(256) void drr_direct_kernel(
    const float* __restrict__ vol,
    const float* __restrict__ rt_inv, const float* __restrict__ k_inv,
    const float* __restrict__ sdd, const float* __restrict__ isocenter,
    const float* __restrict__ origin, const float* __restrict__ spacing,
    const float* __restrict__ rot, const float* __restrict__ xyz,
    float* __restrict__ out)
{
    __shared__ SetupOut S;
    if (threadIdx.x == 0 && threadIdx.y == 0)
        compute_setup(rt_inv, k_inv, sdd, isocenter, origin, spacing, rot, xyz, &S);
    __syncthreads();

    const int seg = threadIdx.x & 1;
    const int iy = blockIdx.x * 32 + (threadIdx.x >> 1);
    const int ix = blockIdx.y * 4  + threadIdx.y;
    const RayState r = ray_setup(&S, ix, iy);

    float acc = 0.f;
    if (r.any) {
        #pragma unroll 4
        for (int i = r.imin + seg; i <= r.imax; i += 2) {
            const float frac = ((float)i + 0.5f) * (1.0f / (float)NSTEPS);
            const float vx = fmaf(r.Bx, frac, r.Ax);
            const float vy = fmaf(r.By, frac, r.Ay);
            const float vz = fmaf(r.Bz, frac, r.Az);
            const bool inside = (vx >= 0.f) && (vx <= DM1) &&
                                (vy >= 0.f) && (vy <= DM1) &&
                                (vz >= 0.f) && (vz <= DM1);
            const float cx = fminf(fmaxf(vx, 0.f), DM1);
            const float cy = fminf(fmaxf(vy, 0.f), DM1);
            const float cz = fminf(fmaxf(vz, 0.f), DM1);
            const float px = floorf(cx), py = floorf(cy), pz = floorf(cz);
            const int x0 = (int)px, y0 = (int)py, z0 = (int)pz;
            const int x1 = min(x0 + 1, D - 1);
            const int y1 = min(y0 + 1, D - 1);
            const int z1 = min(z0 + 1, D - 1);
            const float fx = cx - px, fy = cy - py, fz = cz - pz;
            const float gx = 1.f - fx, gy = 1.f - fy, gz = 1.f - fz;

            const int base = (x0 << 16) + (y0 << 8);
            const int bx = (x1 - x0) << 16;
            const int by = (y1 - y0) << 8;

            const float v000 = vol[base + z0],           v001 = vol[base + z1];
            const float v010 = vol[base + by + z0],      v011 = vol[base + by + z1];
            const float v100 = vol[base + bx + z0],      v101 = vol[base + bx + z1];
            const float v110 = vol[base + bx + by + z0], v111 = vol[base + bx + by + z1];

            const float c00 = v000*gz + v001*fz;
            const float c01 = v010*gz + v011*fz;
            const float c10 = v100*gz + v101*fz;
            const float c11 = v110*gz + v111*fz;
            const float samp = (c00*gy + c01*fy)*gx + (c10*gy + c11*fy)*fx;
            acc += inside ? samp : 0.f;
        }
    }
    acc += __shfl_xor(acc, 1);
    if (seg == 0)
        out[iy * W + ix] = acc * r.seglen;
}

extern "C" void kernel_launch(void* const* d_in, const int* in_sizes, int n_in,
                              void* d_out, int out_size, void* d_ws, size_t ws_size,
                              hipStream_t stream) {
    const float* vol      = (const float*)d_in[0];
    const float* rt_inv   = (const float*)d_in[1];
    const float* k_inv    = (const float*)d_in[2];
    const float* sdd      = (const float*)d_in[3];
    const float* iso      = (const float*)d_in[4];
    const float* origin   = (const float*)d_in[5];
    const float* spacing  = (const float*)d_in[6];
    const float* rot      = (const float*)d_in[7];
    const float* xyz      = (const float*)d_in[8];
    float* out = (float*)d_out;

    if (ws_size >= PAIR_WS_BYTES + 4096) {
        // masked pair path: setup+mask, then masked pair repack, then raycast
        unsigned int* wsp = (unsigned int*)d_ws;
        SetupOut* sp = (SetupOut*)((char*)d_ws + PAIR_WS_BYTES);
        unsigned char* gmask = (unsigned char*)d_ws + PAIR_WS_BYTES + 512;

        setup_kernel2<<<1, 256, 0, stream>>>(rt_inv, k_inv, sdd, iso, origin,
                                             spacing, rot, xyz, sp, gmask);
        repack_pair_t<<<dim3(D, 2, 4), 256, 0, stream>>>(vol, wsp, gmask);
        drr_pair_kernel<<<dim3(4096), dim3(64, 4), 0, stream>>>(wsp, sp, out);
    } else {
        drr_direct_kernel<<<dim3(H / 32, W / 4), dim3(64, 4), 0, stream>>>(
            vol, rt_inv, k_inv, sdd, iso, origin, spacing, rot, xyz, out);
    }
}